// Round 10
// baseline (388.410 us; speedup 1.0000x reference)
//
#include <hip/hip_runtime.h>

#define DEV __device__ __forceinline__

typedef __attribute__((ext_vector_type(4))) float f32x4;
typedef __attribute__((ext_vector_type(4))) unsigned short u16x4;
typedef __attribute__((ext_vector_type(8))) __bf16 bf16x8;

constexpr int NB = 16, SL = 2048, EM = 1024, DKD = 128;

DEV unsigned short f2bf(float f) {           // fp32 -> bf16 RNE
  unsigned int u = __float_as_uint(f);
  u += 0x7FFFu + ((u >> 16) & 1u);
  return (unsigned short)(u >> 16);
}

DEV f32x4 mfma16(bf16x8 a, bf16x8 b, f32x4 c) {
  return __builtin_amdgcn_mfma_f32_16x16x32_bf16(a, b, c, 0, 0, 0);
}

// async global->LDS DMA, 16B per lane; lds dst = wave-uniform base + lane*16
DEV void dma16(const void* g, void* l) {
  __builtin_amdgcn_global_load_lds(
      (const __attribute__((address_space(1))) unsigned int*)g,
      (__attribute__((address_space(3))) unsigned int*)l, 16, 0, 0);
}

DEV bf16x8 cvt8(f32x4 a, f32x4 b) {
  bf16x8 r;
  r[0] = (__bf16)a[0]; r[1] = (__bf16)a[1]; r[2] = (__bf16)a[2]; r[3] = (__bf16)a[3];
  r[4] = (__bf16)b[0]; r[5] = (__bf16)b[1]; r[6] = (__bf16)b[2]; r[7] = (__bf16)b[3];
  return r;
}

// ---------------------------------------------------------------------------
// prep_w: Wq/Wk/Wv fp32 [1024][128] -> bf16, tiled+swizzled. Block 0 also
// zeroes the mean-V accumulator mvg[NB][128].
// Chunk t = ((m*16 + kc)*128 + n)*8 + p holds W_m[k = kc*64 + (p^(n&7))*8 + e][n].
// ---------------------------------------------------------------------------
__global__ __launch_bounds__(256) void prep_w(
    const float* __restrict__ Wq, const float* __restrict__ Wk,
    const float* __restrict__ Wv, unsigned short* __restrict__ Wt,
    float* __restrict__ mvg)
{
  __shared__ unsigned short T[64 * 128];     // [kk][n] bf16
  const int tid = threadIdx.x;
  if (blockIdx.x == 0) {
    #pragma unroll
    for (int i = 0; i < NB * DKD / 256; ++i) mvg[i * 256 + tid] = 0.f;
  }
  const int m = blockIdx.x >> 4, kc = blockIdx.x & 15;   // 48 blocks
  const float* W = (m == 0) ? Wq : ((m == 1) ? Wk : Wv);
  #pragma unroll
  for (int it = 0; it < 8; ++it) {
    int idx = it * 256 + tid;                // 2048 f32x4 chunks
    int kk = idx >> 5, n4 = (idx & 31) * 4;
    f32x4 w4 = *(const f32x4*)(W + (size_t)(kc * 64 + kk) * DKD + n4);
    *(u16x4*)&T[kk * 128 + n4] =
        u16x4{ f2bf(w4[0]), f2bf(w4[1]), f2bf(w4[2]), f2bf(w4[3]) };
  }
  __syncthreads();
  #pragma unroll
  for (int it = 0; it < 4; ++it) {
    int idx = it * 256 + tid;                // 1024 out chunks, p fastest
    int p = idx & 7, n = idx >> 3;
    int c = p ^ (n & 7);
    unsigned short v[8];
    #pragma unroll
    for (int e = 0; e < 8; ++e) v[e] = T[(c * 8 + e) * 128 + n];
    size_t t = ((size_t)(m * 16 + kc) * 128 + n) * 8 + p;
    *(u16x4*)(Wt + t * 8)     = u16x4{v[0], v[1], v[2], v[3]};
    *(u16x4*)(Wt + t * 8 + 4) = u16x4{v[4], v[5], v[6], v[7]};
  }
}

// ---------------------------------------------------------------------------
// proj_qk: Q,K = ctx @ {Wq,Wk}. NO LDS, NO BARRIERS. 2x2 wave split:
// wave=(mh,nh): mh=wave>>1 owns 32 rows (2 rt tiles), nh=wave&1 owns 128 cols
// (nh=0 -> Q, nh=1 -> K; 8 nt tiles). A loaded straight to registers (2x dup,
// prefetched one kc ahead); B streamed from L2-resident pre-swizzled Wt (2x
// dup). Waves free-run; compiler inserts counted waitcnts. Dead blocks return.
// B offset (shorts): nh*131072 + kc*8192 + nt*1024 + mm*64 + pl[ks]*8,
// pl[ks] = (ks*4+quad)^(mm&7)  [identical chunk map to the r8 bbase formula].
// ---------------------------------------------------------------------------
__global__ __launch_bounds__(256, 2) void proj_qk(
    const float* __restrict__ ctx, const unsigned short* __restrict__ Wt,
    const int* __restrict__ lens, unsigned short* __restrict__ Qo,
    unsigned short* __restrict__ Kz)
{
  const int tid = threadIdx.x;
  const int wave = tid >> 6, lane = tid & 63;
  const int quad = lane >> 4, mm = lane & 15;
  const int mh = wave >> 1, nh = wave & 1;
  const int rb = blockIdx.x * 64;
  const int len = lens[blockIdx.x >> 5];
  if ((rb & (SL - 1)) >= len) return;          // dead block: outputs never read

  f32x4 acc[2][8];
  #pragma unroll
  for (int rt = 0; rt < 2; ++rt)
    #pragma unroll
    for (int nt = 0; nt < 8; ++nt) acc[rt][nt] = f32x4{0.f, 0.f, 0.f, 0.f};

  const float* arow[2];
  #pragma unroll
  for (int rt = 0; rt < 2; ++rt)
    arow[rt] = ctx + (size_t)(rb + mh * 32 + rt * 16 + mm) * EM + quad * 8;

  const int pl0 = (quad)     ^ (mm & 7);
  const int pl1 = (4 + quad) ^ (mm & 7);
  const unsigned short* bb = Wt + (size_t)nh * 131072 + mm * 64;

  // A(0) -> registers
  f32x4 An[2][2][2];
  #pragma unroll
  for (int rt = 0; rt < 2; ++rt)
    #pragma unroll
    for (int ks = 0; ks < 2; ++ks) {
      An[rt][ks][0] = *(const f32x4*)(arow[rt] + ks * 32);
      An[rt][ks][1] = *(const f32x4*)(arow[rt] + ks * 32 + 4);
    }

  #pragma unroll 1
  for (int kc = 0; kc < 16; ++kc) {
    bf16x8 af[2][2];
    #pragma unroll
    for (int rt = 0; rt < 2; ++rt)
      #pragma unroll
      for (int ks = 0; ks < 2; ++ks)
        af[rt][ks] = cvt8(An[rt][ks][0], An[rt][ks][1]);
    if (kc < 15) {                              // prefetch A(kc+1) (uniform)
      #pragma unroll
      for (int rt = 0; rt < 2; ++rt)
        #pragma unroll
        for (int ks = 0; ks < 2; ++ks) {
          An[rt][ks][0] = *(const f32x4*)(arow[rt] + (kc + 1) * 64 + ks * 32);
          An[rt][ks][1] = *(const f32x4*)(arow[rt] + (kc + 1) * 64 + ks * 32 + 4);
        }
    }
    const unsigned short* bk = bb + (size_t)kc * 8192;
    #pragma unroll
    for (int nt = 0; nt < 8; ++nt) {
      bf16x8 b0 = *(const bf16x8*)(bk + nt * 1024 + pl0 * 8);
      bf16x8 b1 = *(const bf16x8*)(bk + nt * 1024 + pl1 * 8);
      #pragma unroll
      for (int rt = 0; rt < 2; ++rt)
        acc[rt][nt] = mfma16(af[rt][0], b0, acc[rt][nt]);
      #pragma unroll
      for (int rt = 0; rt < 2; ++rt)
        acc[rt][nt] = mfma16(af[rt][1], b1, acc[rt][nt]);
    }
  }

  const float SCALE = 1.4426950408889634f * 0.08838834764831845f; // log2e/sqrt(128)
  #pragma unroll
  for (int rt = 0; rt < 2; ++rt)
    #pragma unroll
    for (int nt = 0; nt < 8; ++nt) {
      #pragma unroll
      for (int reg = 0; reg < 4; ++reg) {
        const int row = rb + mh * 32 + rt * 16 + quad * 4 + reg;
        const int j = row & (SL - 1);
        const float val = acc[rt][nt][reg];
        const int d = nt * 16 + mm;
        if (nh == 0) {
          Qo[(size_t)row * DKD + d] = f2bf(val * ((j < len) ? SCALE : 0.f));
        } else {
          Kz[(size_t)row * DKD + (((d >> 3) ^ (j & 15)) * 8) + (d & 7)] = f2bf(val);
        }
      }
    }
}

// ---------------------------------------------------------------------------
// proj_v: V = x @ Wv, same no-barrier 2x2 structure (cols 128 -> nh*64 + 4 nt
// tiles). Epilogue: swizzled Vz store + per-batch column-sum into mvg.
// B offset: 2*131072 + kc*8192 + (nh*4+nt)*1024 + mm*64 + pl[ks]*8.
// ---------------------------------------------------------------------------
__global__ __launch_bounds__(256, 2) void proj_v(
    const float* __restrict__ x, const unsigned short* __restrict__ Wt,
    const int* __restrict__ lens, unsigned short* __restrict__ Vz,
    float* __restrict__ mvg)
{
  const int tid = threadIdx.x;
  const int wave = tid >> 6, lane = tid & 63;
  const int quad = lane >> 4, mm = lane & 15;
  const int mh = wave >> 1, nh = wave & 1;
  const int rb = blockIdx.x * 64;
  const int bidx = blockIdx.x >> 5;
  const int len = lens[bidx];
  if ((rb & (SL - 1)) >= len) return;          // dead block: outputs never read

  f32x4 acc[2][4];
  #pragma unroll
  for (int rt = 0; rt < 2; ++rt)
    #pragma unroll
    for (int nt = 0; nt < 4; ++nt) acc[rt][nt] = f32x4{0.f, 0.f, 0.f, 0.f};

  const float* arow[2];
  #pragma unroll
  for (int rt = 0; rt < 2; ++rt)
    arow[rt] = x + (size_t)(rb + mh * 32 + rt * 16 + mm) * EM + quad * 8;

  const int pl0 = (quad)     ^ (mm & 7);
  const int pl1 = (4 + quad) ^ (mm & 7);
  const unsigned short* bb = Wt + (size_t)2 * 131072 + (size_t)nh * 4096 + mm * 64;

  f32x4 An[2][2][2];
  #pragma unroll
  for (int rt = 0; rt < 2; ++rt)
    #pragma unroll
    for (int ks = 0; ks < 2; ++ks) {
      An[rt][ks][0] = *(const f32x4*)(arow[rt] + ks * 32);
      An[rt][ks][1] = *(const f32x4*)(arow[rt] + ks * 32 + 4);
    }

  #pragma unroll 1
  for (int kc = 0; kc < 16; ++kc) {
    bf16x8 af[2][2];
    #pragma unroll
    for (int rt = 0; rt < 2; ++rt)
      #pragma unroll
      for (int ks = 0; ks < 2; ++ks)
        af[rt][ks] = cvt8(An[rt][ks][0], An[rt][ks][1]);
    if (kc < 15) {
      #pragma unroll
      for (int rt = 0; rt < 2; ++rt)
        #pragma unroll
        for (int ks = 0; ks < 2; ++ks) {
          An[rt][ks][0] = *(const f32x4*)(arow[rt] + (kc + 1) * 64 + ks * 32);
          An[rt][ks][1] = *(const f32x4*)(arow[rt] + (kc + 1) * 64 + ks * 32 + 4);
        }
    }
    const unsigned short* bk = bb + (size_t)kc * 8192;
    #pragma unroll
    for (int nt = 0; nt < 4; ++nt) {
      bf16x8 b0 = *(const bf16x8*)(bk + nt * 1024 + pl0 * 8);
      bf16x8 b1 = *(const bf16x8*)(bk + nt * 1024 + pl1 * 8);
      #pragma unroll
      for (int rt = 0; rt < 2; ++rt)
        acc[rt][nt] = mfma16(af[rt][0], b0, acc[rt][nt]);
      #pragma unroll
      for (int rt = 0; rt < 2; ++rt)
        acc[rt][nt] = mfma16(af[rt][1], b1, acc[rt][nt]);
    }
  }

  #pragma unroll
  for (int rt = 0; rt < 2; ++rt)
    #pragma unroll
    for (int nt = 0; nt < 4; ++nt) {
      const int d = nh * 64 + nt * 16 + mm;
      const int row0 = rb + mh * 32 + rt * 16 + quad * 4;
      const int b = row0 >> 11, j0 = row0 & (SL - 1);
      u16x4 pk = u16x4{ f2bf(acc[rt][nt][0]), f2bf(acc[rt][nt][1]),
                        f2bf(acc[rt][nt][2]), f2bf(acc[rt][nt][3]) };
      size_t off = (size_t)b * DKD * SL + (size_t)d * SL + (j0 & ~63)
                 + ((((j0 >> 3) & 7) ^ (d & 7)) * 8) + (j0 & 7);
      *(u16x4*)(Vz + off) = pk;
    }

  // mean-V accumulation: sum valid rows (j < len), f32, one atomic/(d, mh)
  const int jb = rb & (SL - 1);
  #pragma unroll
  for (int nt = 0; nt < 4; ++nt) {
    const int d = nh * 64 + nt * 16 + mm;
    float part = 0.f;
    #pragma unroll
    for (int rt = 0; rt < 2; ++rt) {
      const int jr = jb + mh * 32 + rt * 16 + quad * 4;
      #pragma unroll
      for (int reg = 0; reg < 4; ++reg)
        if (jr + reg < len) part += acc[rt][nt][reg];
    }
    part += __shfl_xor(part, 16);            // quad ^ 1
    part += __shfl_xor(part, 32);            // quad ^ 2
    if (quad == 0) atomicAdd(mvg + bidx * DKD + d, part);
  }
}

// ---------------------------------------------------------------------------
// attn: flash attention, split-k within block (r9, verified). 512 threads:
// wg=wave&3 owns 16 q-rows; wh=wave>>2 owns one 64-wide k-half of each
// 128-wide k-block; independent online-softmax states merged once at end.
// ---------------------------------------------------------------------------
__global__ __launch_bounds__(512, 2) void attn(
    const unsigned short* __restrict__ Qw, const unsigned short* __restrict__ Kz,
    const unsigned short* __restrict__ Vz, const float* __restrict__ mvg,
    const int* __restrict__ lens, float* __restrict__ out)
{
  __shared__ unsigned short Ks[2][128 * 128];    // 64 KiB
  __shared__ unsigned short Vs[2][2][128 * 64];  // 64 KiB
  __shared__ unsigned short Ps[8][16 * 72];      // 18 KiB
  const int tid = threadIdx.x;
  const int wave = tid >> 6, lane = tid & 63;
  const int quad = lane >> 4, mm = lane & 15;
  const int wg = wave & 3;                       // q-row group
  const int wh = wave >> 2;                      // k-half
  const int b = blockIdx.y;
  const int qb = ((int)gridDim.x - 1 - (int)blockIdx.x) * 64;  // heavy blocks first
  const int len = lens[b];

  if (qb >= len) {
    const int dd = (tid & 31) * 4;
    const int r0 = tid >> 5;                     // 0..15
    const f32x4 m4 = *(const f32x4*)(mvg + b * DKD + dd);
    const float inv = 1.0f / (float)len;
    const f32x4 val = f32x4{ m4[0]*inv, m4[1]*inv, m4[2]*inv, m4[3]*inv };
    #pragma unroll
    for (int it = 0; it < 4; ++it) {
      const int row = qb + it * 16 + r0;
      *(f32x4*)(out + ((size_t)b * SL + row) * DKD + dd) = val;
    }
    return;
  }

  const int kend = min(qb + 64, len);
  const int nblk = (kend + 127) >> 7;            // 128-wide k-blocks
  const int irow0 = qb + wg * 16 + quad * 4;

  bf16x8 aQ[4];
  {
    const unsigned short* qbase =
        Qw + (size_t)(b * SL + qb + wg * 16 + mm) * DKD + quad * 8;
    #pragma unroll
    for (int cc = 0; cc < 4; ++cc) aQ[cc] = *(const bf16x8*)(qbase + cc * 32);
  }
  bf16x8 onesb;
  #pragma unroll
  for (int i = 0; i < 8; ++i) onesb[i] = (__bf16)1.0f;

  float mr[4];
  #pragma unroll
  for (int r = 0; r < 4; ++r) mr[r] = -__builtin_inff();
  f32x4 acc[8];
  #pragma unroll
  for (int i = 0; i < 8; ++i) acc[i] = f32x4{0.f,0.f,0.f,0.f};
  f32x4 accl = f32x4{0.f,0.f,0.f,0.f};           // l = P @ ones (this half)

  #pragma unroll
  for (int it = 0; it < 4; ++it) {
    int s = it * 512 + tid;
    dma16(Kz + (size_t)(b * SL) * DKD + (size_t)s * 8,
          (char*)Ks[0] + (it * 512 + wave * 64) * 16);
  }
  #pragma unroll
  for (int h = 0; h < 2; ++h)
    #pragma unroll
    for (int it = 0; it < 2; ++it) {
      int s = it * 512 + tid;
      int d = s >> 3, p = s & 7;
      dma16(Vz + (size_t)b * DKD * SL + (size_t)d * SL + h * 64 + p * 8,
            (char*)Vs[0][h] + (it * 512 + wave * 64) * 16);
    }

  #pragma unroll 1
  for (int blk = 0; blk < nblk; ++blk) {
    const int kb = blk * 128;
    __syncthreads();                             // drains DMA(blk)
    if (blk + 1 < nblk) {
      const int kb1 = kb + 128;
      const int nb = (blk + 1) & 1;
      #pragma unroll
      for (int it = 0; it < 4; ++it) {
        int s = it * 512 + tid;
        dma16(Kz + (size_t)(b * SL + kb1) * DKD + (size_t)s * 8,
              (char*)Ks[nb] + (it * 512 + wave * 64) * 16);
      }
      #pragma unroll
      for (int h = 0; h < 2; ++h)
        #pragma unroll
        for (int it = 0; it < 2; ++it) {
          int s = it * 512 + tid;
          int d = s >> 3, p = s & 7;
          dma16(Vz + (size_t)b * DKD * SL + (size_t)d * SL + (kb1 + h * 64) + p * 8,
                (char*)Vs[nb][h] + (it * 512 + wave * 64) * 16);
        }
    }
    const unsigned short* kbuf = Ks[blk & 1];
    const unsigned short* vbuf = Vs[blk & 1][wh];
    const int kbh = kb + wh * 64;

    f32x4 s4[4];
    __builtin_amdgcn_s_setprio(1);
    #pragma unroll
    for (int nt = 0; nt < 4; ++nt) {
      f32x4 c = f32x4{0.f,0.f,0.f,0.f};
      const int j = wh * 64 + nt * 16 + mm;
      #pragma unroll
      for (int cc = 0; cc < 4; ++cc) {
        const int pp = (cc * 4 + quad) ^ mm;
        bf16x8 kf = *(const bf16x8*)(kbuf + j * 128 + pp * 8);
        c = mfma16(aQ[cc], kf, c);
      }
      s4[nt] = c;
    }
    __builtin_amdgcn_s_setprio(0);

    float alpha[4];
    #pragma unroll
    for (int reg = 0; reg < 4; ++reg) {
      const int jl = min(irow0 + reg + 1, len);
      float v0 = (kbh + mm      < jl) ? s4[0][reg] : -__builtin_inff();
      float v1 = (kbh + 16 + mm < jl) ? s4[1][reg] : -__builtin_inff();
      float v2 = (kbh + 32 + mm < jl) ? s4[2][reg] : -__builtin_inff();
      float v3 = (kbh + 48 + mm < jl) ? s4[3][reg] : -__builtin_inff();
      float mx = fmaxf(fmaxf(v0, v1), fmaxf(v2, v3));
      #pragma unroll
      for (int xm = 1; xm < 16; xm <<= 1) mx = fmaxf(mx, __shfl_xor(mx, xm));
      const float mn = fmaxf(fmaxf(mr[reg], mx), -1e30f);
      alpha[reg] = __builtin_amdgcn_exp2f(mr[reg] - mn);
      const float p0 = __builtin_amdgcn_exp2f(v0 - mn);
      const float p1 = __builtin_amdgcn_exp2f(v1 - mn);
      const float p2 = __builtin_amdgcn_exp2f(v2 - mn);
      const float p3 = __builtin_amdgcn_exp2f(v3 - mn);
      mr[reg] = mn;
      const int prow = quad * 4 + reg;
      Ps[wave][prow * 72 + mm]      = f2bf(p0);
      Ps[wave][prow * 72 + 16 + mm] = f2bf(p1);
      Ps[wave][prow * 72 + 32 + mm] = f2bf(p2);
      Ps[wave][prow * 72 + 48 + mm] = f2bf(p3);
    }
    #pragma unroll
    for (int nt = 0; nt < 8; ++nt) {
      f32x4 a = acc[nt];
      a[0] *= alpha[0]; a[1] *= alpha[1]; a[2] *= alpha[2]; a[3] *= alpha[3];
      acc[nt] = a;
    }
    accl[0] *= alpha[0]; accl[1] *= alpha[1];
    accl[2] *= alpha[2]; accl[3] *= alpha[3];
    __asm__ volatile("s_waitcnt lgkmcnt(0)" ::: "memory");  // P writes -> reads
    bf16x8 aP[2];
    #pragma unroll
    for (int ks = 0; ks < 2; ++ks)
      aP[ks] = *(const bf16x8*)(&Ps[wave][mm * 72 + ks * 32 + quad * 8]);
    __builtin_amdgcn_s_setprio(1);
    #pragma unroll
    for (int ks = 0; ks < 2; ++ks) {
      #pragma unroll
      for (int nt = 0; nt < 8; ++nt) {
        const int pp = (ks * 4 + quad) ^ (mm & 7);
        bf16x8 vf = *(const bf16x8*)(vbuf + (nt * 16 + mm) * 64 + pp * 8);
        acc[nt] = mfma16(aP[ks], vf, acc[nt]);
      }
      accl = mfma16(aP[ks], onesb, accl);
    }
    __builtin_amdgcn_s_setprio(0);
  }

  // ---- merge halves (wh=1 -> LDS scratch in dead Ks; wh=0 merges+writes) ----
  __syncthreads();
  float* mrg = (float*)&Ks[0][0];                // 41*256*4 = 41 KiB
  if (wh == 1) {
    float* p = mrg + (wg * 64 + lane) * 41;
    #pragma unroll
    for (int r = 0; r < 4; ++r) p[r] = mr[r];
    #pragma unroll
    for (int r = 0; r < 4; ++r) p[4 + r] = accl[r];
    #pragma unroll
    for (int nt = 0; nt < 8; ++nt)
      #pragma unroll
      for (int r = 0; r < 4; ++r) p[8 + nt * 4 + r] = acc[nt][r];
  }
  __syncthreads();
  if (wh == 0) {
    const float* p = mrg + (wg * 64 + lane) * 41;
    #pragma unroll
    for (int reg = 0; reg < 4; ++reg) {
      const float m1 = p[reg], l1 = p[4 + reg];
      const float m = fmaxf(mr[reg], m1);
      const float f0 = __builtin_amdgcn_exp2f(mr[reg] - m);
      const float f1 = __builtin_amdgcn_exp2f(m1 - m);
      const float rl = 1.0f / (accl[reg] * f0 + l1 * f1);
      const size_t base = ((size_t)b * SL + irow0 + reg) * DKD + mm;
      #pragma unroll
      for (int nt = 0; nt < 8; ++nt)
        out[base + nt * 16] = (acc[nt][reg] * f0 + p[8 + nt * 4 + reg] * f1) * rl;
    }
  }
}

// ---------------------------------------------------------------------------
extern "C" void kernel_launch(void* const* d_in, const int* in_sizes, int n_in,
                              void* d_out, int out_size, void* d_ws, size_t ws_size,
                              hipStream_t stream) {
  const float* x    = (const float*)d_in[0];
  const float* ctx  = (const float*)d_in[1];
  const int*   lens = (const int*)d_in[2];
  const float* Wq   = (const float*)d_in[3];
  const float* Wk   = (const float*)d_in[4];
  const float* Wv   = (const float*)d_in[5];
  float* out = (float*)d_out;

  const size_t QKV = (size_t)NB * SL * DKD * sizeof(unsigned short); // 8 MiB each
  const size_t WTSZ = (size_t)3 * 16 * 128 * 8 * 8 * sizeof(unsigned short); // 768 KiB
  const size_t MVSZ = (size_t)NB * DKD * sizeof(float);              // 8 KiB
  if (ws_size < 3 * QKV + WTSZ + MVSZ) return;
  unsigned short* Qws = (unsigned short*)d_ws;
  unsigned short* Kzs = (unsigned short*)((char*)d_ws + QKV);
  unsigned short* Vzs = (unsigned short*)((char*)d_ws + 2 * QKV);
  unsigned short* Wt  = (unsigned short*)((char*)d_ws + 3 * QKV);
  float*          mvg = (float*)((char*)d_ws + 3 * QKV + WTSZ);

  prep_w <<<dim3(48), 256, 0, stream>>>(Wq, Wk, Wv, Wt, mvg);
  proj_qk<<<dim3(NB * SL / 64), 256, 0, stream>>>(ctx, Wt, lens, Qws, Kzs);
  proj_v <<<dim3(NB * SL / 64), 256, 0, stream>>>(x, Wt, lens, Vzs, mvg);
  attn   <<<dim3(SL / 64, NB), 512, 0, stream>>>(Qws, Kzs, Vzs, mvg, lens, out);
}